// Round 1
// baseline (128.239 us; speedup 1.0000x reference)
//
#include <hip/hip_runtime.h>
#include <stdint.h>

// ScoreNet: S[b] = (x_b Wq^T)(x_b Wk^T)^T * (1/sqrt(R)) + diag(x_b Wd^T + bd), * max(ls, 0.01)
// B=16, L=2048 -> N=1024, C=256, H*R=192.

#define HD_SCALE 0.17677669529663687f  // 1/sqrt(32)

typedef __bf16 bf16_t;
typedef bf16_t bf16x8 __attribute__((ext_vector_type(8)));
typedef float f32x4 __attribute__((ext_vector_type(4)));

__device__ __forceinline__ unsigned short f2bf(float f) {
  // round-to-nearest-even fp32 -> bf16 bits
  unsigned int u = __float_as_uint(f);
  unsigned int r = (u + 0x7fffu + ((u >> 16) & 1u)) >> 16;
  return (unsigned short)r;
}

__device__ __forceinline__ void gload16(const void* g, void* l) {
  // async global->LDS, 16B per lane; LDS dest = wave-uniform base + lane*16
  __builtin_amdgcn_global_load_lds(
      (const __attribute__((address_space(1))) void*)g,
      (__attribute__((address_space(3))) void*)l, 16, 0, 0);
}

// ---------------------------------------------------------------------------
// Kernel 1: pack [Wq; Wk] (each 192x256 fp32) into bf16 (384x256)
// ---------------------------------------------------------------------------
__global__ __launch_bounds__(256) void k_wconv(const float* __restrict__ Wq,
                                               const float* __restrict__ Wk,
                                               unsigned short* __restrict__ Wqkb) {
  int idx = blockIdx.x * 256 + threadIdx.x;  // 0..98303
  float v = (idx < 49152) ? Wq[idx] : Wk[idx - 49152];
  Wqkb[idx] = f2bf(v);
}

// ---------------------------------------------------------------------------
// Kernel 2: fold pairs of rows (mean) -> xb (bf16), and d = x.Wd + bd (fp32)
// One wave per output row (256 cols / 64 lanes = float4 each).
// ---------------------------------------------------------------------------
__global__ __launch_bounds__(256) void k_fold(const float* __restrict__ feats,
                                              const float* __restrict__ Wd,
                                              const float* __restrict__ bd,
                                              unsigned short* __restrict__ xb,
                                              float* __restrict__ dvec) {
  const int t = threadIdx.x;
  const int wave = t >> 6, lane = t & 63;
  const int gr = blockIdx.x * 4 + wave;  // global row = b*1024 + n, 0..16383
  const int b = gr >> 10, n = gr & 1023;
  const int c = lane * 4;

  const float* r0 = feats + (size_t)(b * 2049 + 1 + 2 * n) * 256 + c;
  float4 p0 = *(const float4*)r0;
  float4 p1 = *(const float4*)(r0 + 256);
  float4 wv = *(const float4*)(Wd + c);

  float x0 = (p0.x + p1.x) * 0.5f;
  float x1 = (p0.y + p1.y) * 0.5f;
  float x2 = (p0.z + p1.z) * 0.5f;
  float x3 = (p0.w + p1.w) * 0.5f;

  ushort4 xs;
  xs.x = f2bf(x0); xs.y = f2bf(x1); xs.z = f2bf(x2); xs.w = f2bf(x3);
  *(ushort4*)&xb[(size_t)gr * 256 + c] = xs;

  float dot = x0 * wv.x + x1 * wv.y + x2 * wv.z + x3 * wv.w;
#pragma unroll
  for (int o = 32; o > 0; o >>= 1) dot += __shfl_down(dot, o, 64);
  if (lane == 0) dvec[gr] = dot + bd[0];
}

// ---------------------------------------------------------------------------
// Kernel 3: projection GEMM  QK[16384][384] = xb[16384][256] @ Wqkb[384][256]^T
// 128x128 tile, BK=32, 4 waves in 2x2, each wave 4x4 tiles of 16x16x32 MFMA.
// ---------------------------------------------------------------------------
__global__ __launch_bounds__(256) void k_proj(const unsigned short* __restrict__ xb,
                                              const unsigned short* __restrict__ Wqkb,
                                              unsigned short* __restrict__ QK) {
  __shared__ unsigned short As[128 * 32];  // 8 KB
  __shared__ unsigned short Bs[128 * 32];  // 8 KB
  const int t = threadIdx.x;
  const int w = t >> 6, l = t & 63;
  const int m0 = blockIdx.x * 128;  // row tile in 16384
  const int n0 = blockIdx.y * 128;  // col tile in 384
  const int wm = w >> 1, wn = w & 1;
  const int quad = l >> 4, lr = l & 15;

  f32x4 acc[4][4];
#pragma unroll
  for (int i = 0; i < 4; ++i)
#pragma unroll
    for (int j = 0; j < 4; ++j) acc[i][j] = (f32x4){0.f, 0.f, 0.f, 0.f};

  for (int kk = 0; kk < 8; ++kk) {
    const int k0 = kk * 32;
    __syncthreads();
#pragma unroll
    for (int i = 0; i < 2; ++i) {
      const int e = w * 128 + i * 64 + l;  // 16B chunk index, 512 per tile
      const int row = e >> 2, kc = e & 3;
      gload16(xb + (size_t)(m0 + row) * 256 + k0 + kc * 8,
              &As[(w * 128 + i * 64) * 8]);
      gload16(Wqkb + (size_t)(n0 + row) * 256 + k0 + kc * 8,
              &Bs[(w * 128 + i * 64) * 8]);
    }
    __syncthreads();

    bf16x8 a[4], bfr[4];
#pragma unroll
    for (int i = 0; i < 4; ++i)
      a[i] = *(const bf16x8*)&As[(wm * 64 + i * 16 + lr) * 32 + quad * 8];
#pragma unroll
    for (int j = 0; j < 4; ++j)
      bfr[j] = *(const bf16x8*)&Bs[(wn * 64 + j * 16 + lr) * 32 + quad * 8];
#pragma unroll
    for (int i = 0; i < 4; ++i)
#pragma unroll
      for (int j = 0; j < 4; ++j)
        acc[i][j] = __builtin_amdgcn_mfma_f32_16x16x32_bf16(a[i], bfr[j],
                                                            acc[i][j], 0, 0, 0);
  }

#pragma unroll
  for (int i = 0; i < 4; ++i)
#pragma unroll
    for (int j = 0; j < 4; ++j)
#pragma unroll
      for (int r = 0; r < 4; ++r) {
        const int row = m0 + wm * 64 + i * 16 + quad * 4 + r;
        const int col = n0 + wn * 64 + j * 16 + lr;
        QK[(size_t)row * 384 + col] = f2bf(acc[i][j][r]);
      }
}

// ---------------------------------------------------------------------------
// Kernel 4: S[b] = Q[b] @ K[b]^T * HD_SCALE (+ diag d) * ls
// Q = QK[b*1024+n][0:192], K = QK[b*1024+m][192:384]. K-dim = 192 (6 steps).
// ---------------------------------------------------------------------------
__global__ __launch_bounds__(256) void k_score(const unsigned short* __restrict__ QK,
                                               const float* __restrict__ dvec,
                                               const float* __restrict__ logit_scale,
                                               float* __restrict__ out) {
  __shared__ unsigned short As[128 * 32];
  __shared__ unsigned short Bs[128 * 32];
  const int t = threadIdx.x;
  const int w = t >> 6, l = t & 63;
  const int mt = blockIdx.x, nt = blockIdx.y, b = blockIdx.z;
  const int m0 = mt * 128;  // cols of S (K rows)
  const int n0 = nt * 128;  // rows of S (Q rows)
  const int wm = w >> 1, wn = w & 1;
  const int quad = l >> 4, lr = l & 15;
  const size_t qbase = (size_t)b * 1024 * 384;

  f32x4 acc[4][4];
#pragma unroll
  for (int i = 0; i < 4; ++i)
#pragma unroll
    for (int j = 0; j < 4; ++j) acc[i][j] = (f32x4){0.f, 0.f, 0.f, 0.f};

  for (int kk = 0; kk < 6; ++kk) {
    const int k0 = kk * 32;
    __syncthreads();
#pragma unroll
    for (int i = 0; i < 2; ++i) {
      const int e = w * 128 + i * 64 + l;
      const int row = e >> 2, kc = e & 3;
      gload16(QK + qbase + (size_t)(n0 + row) * 384 + k0 + kc * 8,
              &As[(w * 128 + i * 64) * 8]);
      gload16(QK + qbase + (size_t)(m0 + row) * 384 + 192 + k0 + kc * 8,
              &Bs[(w * 128 + i * 64) * 8]);
    }
    __syncthreads();

    bf16x8 a[4], bfr[4];
#pragma unroll
    for (int i = 0; i < 4; ++i)
      a[i] = *(const bf16x8*)&As[(wm * 64 + i * 16 + lr) * 32 + quad * 8];
#pragma unroll
    for (int j = 0; j < 4; ++j)
      bfr[j] = *(const bf16x8*)&Bs[(wn * 64 + j * 16 + lr) * 32 + quad * 8];
#pragma unroll
    for (int i = 0; i < 4; ++i)
#pragma unroll
      for (int j = 0; j < 4; ++j)
        acc[i][j] = __builtin_amdgcn_mfma_f32_16x16x32_bf16(a[i], bfr[j],
                                                            acc[i][j], 0, 0, 0);
  }

  const float ls = fmaxf(logit_scale[0], 0.01f);
  const bool diag_block = (m0 == n0);
#pragma unroll
  for (int i = 0; i < 4; ++i)
#pragma unroll
    for (int j = 0; j < 4; ++j)
#pragma unroll
      for (int r = 0; r < 4; ++r) {
        const int nr = n0 + wm * 64 + i * 16 + quad * 4 + r;  // S row
        const int mc = m0 + wn * 64 + j * 16 + lr;            // S col
        float v = acc[i][j][r] * HD_SCALE;
        if (diag_block && nr == mc) v += dvec[b * 1024 + nr];
        out[((size_t)b << 20) + (size_t)nr * 1024 + mc] = v * ls;
      }
}

// ---------------------------------------------------------------------------
extern "C" void kernel_launch(void* const* d_in, const int* in_sizes, int n_in,
                              void* d_out, int out_size, void* d_ws, size_t ws_size,
                              hipStream_t stream) {
  const float* feats = (const float*)d_in[0];  // (16, 2049, 256)
  const float* Wq = (const float*)d_in[1];     // (192, 256)
  const float* Wk = (const float*)d_in[2];     // (192, 256)
  const float* Wd = (const float*)d_in[3];     // (1, 256)
  const float* bd = (const float*)d_in[4];     // (1,)
  const float* ls = (const float*)d_in[5];     // scalar
  float* out = (float*)d_out;                  // (16, 1024, 1024) fp32

  uint8_t* ws = (uint8_t*)d_ws;
  unsigned short* xb = (unsigned short*)ws;                          // 8 MB bf16 x
  unsigned short* QK = (unsigned short*)(ws + (8u << 20));           // 12 MB bf16 [Q|K]
  float* dvec = (float*)(ws + (20u << 20));                          // 64 KB fp32 d
  unsigned short* Wqkb = (unsigned short*)(ws + (20u << 20) + (64u << 10));  // 192 KB

  hipLaunchKernelGGL(k_wconv, dim3(384), dim3(256), 0, stream, Wq, Wk, Wqkb);
  hipLaunchKernelGGL(k_fold, dim3(4096), dim3(256), 0, stream, feats, Wd, bd, xb, dvec);
  hipLaunchKernelGGL(k_proj, dim3(128, 3), dim3(256), 0, stream, xb, Wqkb, QK);
  hipLaunchKernelGGL(k_score, dim3(8, 8, 16), dim3(256), 0, stream, QK, dvec, ls, out);
}

// Round 2
// 127.181 us; speedup vs baseline: 1.0083x; 1.0083x over previous
//
#include <hip/hip_runtime.h>
#include <stdint.h>

// ScoreNet: S[b] = (x_b Wq^T)(x_b Wk^T)^T * (1/sqrt(R)) + diag(x_b Wd^T + bd), * max(ls, 0.01)
// B=16, L=2048 -> N=1024, C=256, H*R=192.

#define HD_SCALE 0.17677669529663687f  // 1/sqrt(32)

typedef __bf16 bf16_t;
typedef bf16_t bf16x8 __attribute__((ext_vector_type(8)));
typedef float f32x4 __attribute__((ext_vector_type(4)));

__device__ __forceinline__ unsigned short f2bf(float f) {
  // round-to-nearest-even fp32 -> bf16 bits
  unsigned int u = __float_as_uint(f);
  return (unsigned short)((u + 0x7fffu + ((u >> 16) & 1u)) >> 16);
}

__device__ __forceinline__ void gload16(const void* g, void* l) {
  // async global->LDS, 16B/lane; LDS dest = wave-uniform base + lane*16
  __builtin_amdgcn_global_load_lds(
      (const __attribute__((address_space(1))) void*)g,
      (__attribute__((address_space(3))) void*)l, 16, 0, 0);
}

// ---------------------------------------------------------------------------
// Kernel 1: fold pairs of rows (mean) -> xb (bf16), d = x.Wd + bd (fp32),
// and (first 384 blocks) pack [Wq;Wk] fp32 -> bf16.
// One wave per output row (256 cols / 64 lanes = float4 each).
// ---------------------------------------------------------------------------
__global__ __launch_bounds__(256) void k_prep(const float* __restrict__ feats,
                                              const float* __restrict__ Wq,
                                              const float* __restrict__ Wk,
                                              const float* __restrict__ Wd,
                                              const float* __restrict__ bd,
                                              unsigned short* __restrict__ xb,
                                              float* __restrict__ dvec,
                                              unsigned short* __restrict__ Wqkb) {
  const int t = threadIdx.x;
  if (blockIdx.x < 384) {  // weight conversion: 384*256 = 98304 elements
    const int idx = blockIdx.x * 256 + t;
    const float v = (idx < 49152) ? Wq[idx] : Wk[idx - 49152];
    Wqkb[idx] = f2bf(v);
  }
  const int wave = t >> 6, lane = t & 63;
  const int gr = blockIdx.x * 4 + wave;  // global row = b*1024 + n
  const int b = gr >> 10, n = gr & 1023;
  const int c = lane * 4;

  const float* r0 = feats + (size_t)(b * 2049 + 1 + 2 * n) * 256 + c;
  float4 p0 = *(const float4*)r0;
  float4 p1 = *(const float4*)(r0 + 256);
  float4 wv = *(const float4*)(Wd + c);

  float x0 = (p0.x + p1.x) * 0.5f;
  float x1 = (p0.y + p1.y) * 0.5f;
  float x2 = (p0.z + p1.z) * 0.5f;
  float x3 = (p0.w + p1.w) * 0.5f;

  ushort4 xs;
  xs.x = f2bf(x0); xs.y = f2bf(x1); xs.z = f2bf(x2); xs.w = f2bf(x3);
  *(ushort4*)&xb[(size_t)gr * 256 + c] = xs;

  float dot = x0 * wv.x + x1 * wv.y + x2 * wv.z + x3 * wv.w;
#pragma unroll
  for (int o = 32; o > 0; o >>= 1) dot += __shfl_down(dot, o, 64);
  if (lane == 0) dvec[gr] = dot + bd[0];
}

// ---------------------------------------------------------------------------
// Kernel 2: projection GEMM  QK[16384][384] = xb[16384][256] @ Wqkb[384][256]^T
// 128x128 tile, BK=64 (4 iters), XOR-swizzled LDS (chunk ^= row&7) for
// uniform bank distribution under the global_load_lds layout constraint.
// ---------------------------------------------------------------------------
__global__ __launch_bounds__(256) void k_proj(const unsigned short* __restrict__ xb,
                                              const unsigned short* __restrict__ Wqkb,
                                              unsigned short* __restrict__ QK) {
  __shared__ unsigned short As[128 * 64];  // 16 KB
  __shared__ unsigned short Bs[128 * 64];  // 16 KB
  const int t = threadIdx.x;
  const int w = t >> 6, l = t & 63;
  const int m0 = blockIdx.x * 128;  // row tile in 16384
  const int n0 = blockIdx.y * 128;  // col tile in 384
  const int wm = w >> 1, wn = w & 1;
  const int quad = l >> 4, lr = l & 15;

  f32x4 acc[4][4] = {};

  for (int kk = 0; kk < 4; ++kk) {
    const int k0 = kk * 64;
    __syncthreads();
#pragma unroll
    for (int i = 0; i < 4; ++i) {
      const int e = i * 256 + t;            // 16B-slot index, 1024 per tile
      const int row = e >> 3;
      const int kc = (e & 7) ^ (row & 7);   // swizzled source chunk
      gload16(xb + (size_t)(m0 + row) * 256 + k0 + kc * 8,
              &As[(i * 256 + (w << 6)) * 8]);
      gload16(Wqkb + (size_t)(n0 + row) * 256 + k0 + kc * 8,
              &Bs[(i * 256 + (w << 6)) * 8]);
    }
    __syncthreads();

#pragma unroll
    for (int s = 0; s < 2; ++s) {
      bf16x8 a[4], bb[4];
#pragma unroll
      for (int i = 0; i < 4; ++i) {
        const int row = wm * 64 + i * 16 + lr;
        const int pos = (s * 4 + quad) ^ (row & 7);
        a[i] = *(const bf16x8*)&As[row * 64 + pos * 8];
      }
#pragma unroll
      for (int j = 0; j < 4; ++j) {
        const int row = wn * 64 + j * 16 + lr;
        const int pos = (s * 4 + quad) ^ (row & 7);
        bb[j] = *(const bf16x8*)&Bs[row * 64 + pos * 8];
      }
#pragma unroll
      for (int i = 0; i < 4; ++i)
#pragma unroll
        for (int j = 0; j < 4; ++j)
          acc[i][j] = __builtin_amdgcn_mfma_f32_16x16x32_bf16(a[i], bb[j],
                                                              acc[i][j], 0, 0, 0);
    }
  }

#pragma unroll
  for (int i = 0; i < 4; ++i)
#pragma unroll
    for (int j = 0; j < 4; ++j)
#pragma unroll
      for (int r = 0; r < 4; ++r) {
        const int row = m0 + wm * 64 + i * 16 + quad * 4 + r;
        const int col = n0 + wn * 64 + j * 16 + lr;
        QK[(size_t)row * 384 + col] = f2bf(acc[i][j][r]);
      }
}

// ---------------------------------------------------------------------------
// Kernel 3: S[b] = Q[b] @ K[b]^T * HD_SCALE (+ diag d) * ls
// Q = QK[b*1024+n][0:192], K = QK[b*1024+m][192:384]. BK=64 -> 3 iters.
// ---------------------------------------------------------------------------
__global__ __launch_bounds__(256) void k_score(const unsigned short* __restrict__ QK,
                                               const float* __restrict__ dvec,
                                               const float* __restrict__ logit_scale,
                                               float* __restrict__ out) {
  __shared__ unsigned short As[128 * 64];  // 16 KB
  __shared__ unsigned short Bs[128 * 64];  // 16 KB
  const int t = threadIdx.x;
  const int w = t >> 6, l = t & 63;
  const int mt = blockIdx.x, nt = blockIdx.y, b = blockIdx.z;
  const int m0 = mt * 128;  // cols of S (K rows)
  const int n0 = nt * 128;  // rows of S (Q rows)
  const int wm = w >> 1, wn = w & 1;
  const int quad = l >> 4, lr = l & 15;
  const size_t qbase = (size_t)b * 1024 * 384;

  f32x4 acc[4][4] = {};

  for (int kk = 0; kk < 3; ++kk) {
    const int k0 = kk * 64;
    __syncthreads();
#pragma unroll
    for (int i = 0; i < 4; ++i) {
      const int e = i * 256 + t;
      const int row = e >> 3;
      const int kc = (e & 7) ^ (row & 7);
      gload16(QK + qbase + (size_t)(n0 + row) * 384 + k0 + kc * 8,
              &As[(i * 256 + (w << 6)) * 8]);
      gload16(QK + qbase + (size_t)(m0 + row) * 384 + 192 + k0 + kc * 8,
              &Bs[(i * 256 + (w << 6)) * 8]);
    }
    __syncthreads();

#pragma unroll
    for (int s = 0; s < 2; ++s) {
      bf16x8 a[4], bb[4];
#pragma unroll
      for (int i = 0; i < 4; ++i) {
        const int row = wm * 64 + i * 16 + lr;
        const int pos = (s * 4 + quad) ^ (row & 7);
        a[i] = *(const bf16x8*)&As[row * 64 + pos * 8];
      }
#pragma unroll
      for (int j = 0; j < 4; ++j) {
        const int row = wn * 64 + j * 16 + lr;
        const int pos = (s * 4 + quad) ^ (row & 7);
        bb[j] = *(const bf16x8*)&Bs[row * 64 + pos * 8];
      }
#pragma unroll
      for (int i = 0; i < 4; ++i)
#pragma unroll
        for (int j = 0; j < 4; ++j)
          acc[i][j] = __builtin_amdgcn_mfma_f32_16x16x32_bf16(a[i], bb[j],
                                                              acc[i][j], 0, 0, 0);
    }
  }

  const float ls = fmaxf(logit_scale[0], 0.01f);
  const bool diag_block = (m0 == n0);
#pragma unroll
  for (int i = 0; i < 4; ++i)
#pragma unroll
    for (int j = 0; j < 4; ++j)
#pragma unroll
      for (int r = 0; r < 4; ++r) {
        const int nr = n0 + wm * 64 + i * 16 + quad * 4 + r;  // S row
        const int mc = m0 + wn * 64 + j * 16 + lr;            // S col
        float v = acc[i][j][r] * HD_SCALE;
        if (diag_block && nr == mc) v += dvec[b * 1024 + nr];
        __builtin_nontemporal_store(v * ls,
            &out[((size_t)b << 20) + (size_t)nr * 1024 + mc]);
      }
}

// ---------------------------------------------------------------------------
extern "C" void kernel_launch(void* const* d_in, const int* in_sizes, int n_in,
                              void* d_out, int out_size, void* d_ws, size_t ws_size,
                              hipStream_t stream) {
  const float* feats = (const float*)d_in[0];  // (16, 2049, 256)
  const float* Wq = (const float*)d_in[1];     // (192, 256)
  const float* Wk = (const float*)d_in[2];     // (192, 256)
  const float* Wd = (const float*)d_in[3];     // (1, 256)
  const float* bd = (const float*)d_in[4];     // (1,)
  const float* ls = (const float*)d_in[5];     // scalar
  float* out = (float*)d_out;                  // (16, 1024, 1024) fp32

  uint8_t* ws = (uint8_t*)d_ws;
  unsigned short* xb = (unsigned short*)ws;                          // 8 MB bf16 x
  unsigned short* QK = (unsigned short*)(ws + (8u << 20));           // 12 MB bf16 [Q|K]
  float* dvec = (float*)(ws + (20u << 20));                          // 64 KB fp32 d
  unsigned short* Wqkb = (unsigned short*)(ws + (20u << 20) + (64u << 10));  // 192 KB

  hipLaunchKernelGGL(k_prep, dim3(4096), dim3(256), 0, stream, feats, Wq, Wk, Wd, bd,
                     xb, dvec, Wqkb);
  hipLaunchKernelGGL(k_proj, dim3(128, 3), dim3(256), 0, stream, xb, Wqkb, QK);
  hipLaunchKernelGGL(k_score, dim3(8, 8, 16), dim3(256), 0, stream, QK, dvec, ls, out);
}